// Round 8
// baseline (112.545 us; speedup 1.0000x reference)
//
#include <hip/hip_runtime.h>

#define GRID 32
#define NT 48
#define BLK 256
#define SPLIT 16                 // threads per point; each handles 3 t-rows = 9 tris
#define PPB (BLK / SPLIT)        // 16 points per block
#define NWAVE (BLK / 64)         // 4 waves per block
#define NCELLS (GRID * GRID * GRID)
#define CAP 32                   // fallback wlist capacity
#define CAP2 16                  // slot-order dmin capacity (Poisson(4): P(>16) ~ 1e-6)
#define GSTRIDE 144              // gram slot stride (r4-verified layout)

// Per-edge packed info: bits [0]=base_x, [1]=base_y, [2]=base_z, [4:3]=axis.
// EDGE_BASE[e][axis[e]] == 0 for all 12 edges, so vert = base with comp[axis]=t.
#define EDGE_PACK ( (0ULL<<0) | (9ULL<<5) | (2ULL<<10) | (8ULL<<15) | \
                    (4ULL<<20) | (13ULL<<25) | (6ULL<<30) | (12ULL<<35) | \
                    (16ULL<<40) | (17ULL<<45) | (19ULL<<50) | (18ULL<<55) )

// Squared distance from p to triangle (a,b,c) from the 6 Gram entries of
// Ap=p-a, Bp=p-b, Cp=p-c. Region cascade matches the reference order exactly;
// vertex regions collapse exactly to AA/BB/CC and are applied as cascade-
// ordered overrides. VERBATIM round-4 verified text (absmax 0.0039).
__device__ __forceinline__ float tri_dist_gram(float AA, float AB, float AC,
                                               float BB, float BC, float CC) {
    float d1 = AA - AB, d2 = AA - AC;
    float d3 = AB - BB, d4 = AB - BC;
    float d5 = AC - BC, d6 = AC - CC;
    float d43 = BB - BC;          // == d4 - d3
    float d56 = CC - BC;          // == d5 - d6
    float vc = d1 * d4 - d3 * d2;
    float vb = d5 * d2 - d1 * d6;
    float va = d3 * d6 - d5 * d4;

    bool cbc = (va <= 0.f) & (d43 >= 0.f) & (d56 >= 0.f);
    bool cac = (vb <= 0.f) & (d2 >= 0.f) & (d6 <= 0.f);
    bool ccc = (d6 >= 0.f) & (d5 <= d6);
    bool cab = (vc <= 0.f) & (d1 >= 0.f) & (d3 <= 0.f);
    bool cbb = (d3 >= 0.f) & (d4 <= d3);
    bool caa = (d1 <= 0.f) & (d2 <= 0.f);

    // Chain (later wins): interior -> cbc -> cac -> cab.
    float nv = vb, nw = vc, den = va + vb + vc;
    nw = cbc ? d43 : nw;  den = cbc ? d43 + d56 : den;
    nv = cac ? 0.f : nv;  nw = cac ? d2  : nw;  den = cac ? d2 - d6 : den;
    nv = cab ? d1  : nv;  nw = cab ? 0.f : nw;  den = cab ? d1 - d3 : den;
    bool mode = cbc & !cac & !cab;   // only cbc uses lambda = (0, 1-w, w)

    float dd  = (fabsf(den) > 1e-12f) ? den : 1e-12f;
    float inv = __builtin_amdgcn_rcpf(dd);
    float vp = nv * inv;
    float wp = nw * inv;
    float u = mode ? 0.f : 1.f - vp - wp;
    float v = mode ? 1.f - wp : vp;
    float e1 = fmaf(AC, wp, fmaf(AB, v, AA * u));
    float e2 = fmaf(BC, wp, fmaf(BB, v, AB * u));
    float e3 = fmaf(CC, wp, fmaf(BC, v, AC * u));
    float r  = fmaf(wp, e3, fmaf(v, e2, u * e1));
    // Vertex-region overrides, cascade-ordered.
    r = (ccc & !cab) ? CC : r;
    r = cbb ? BB : r;
    r = caa ? AA : r;
    return r;
}

// Point-major eval, BARRIER-FREE wave-private form.
// A wave (tids 64w..64w+63) owns point-slots pl = 4w..4w+3: v_s / gram /
// pos_s accesses never cross waves. The triangle table gets one copy PER WAVE
// (goff[wid*144 + e]), so no block-wide __syncthreads is needed anywhere —
// same-wave ds_write -> ds_read ordering is guaranteed by lgkmcnt (compiler-
// emitted). Numeric paths (fill window, gram layout, goff packing, cascade)
// are VERBATIM round-4 verified code.
// SLOT=true: binning assigns each point a (cell,pos) slot, dmin slot-ordered
// (dmin[cell][pos][48]); SLOT=false: dmin[pt][48] + wlist.
template<bool SLOT>
__global__ __launch_bounds__(BLK, 8) void eval_kernel(
    const float* __restrict__ offset,     // (3,33,33,33)
    const float* __restrict__ points,     // (N,3)
    const int*   __restrict__ tri_table,  // (48,3,3)
    int*         __restrict__ cnt,        // (NCELLS), zeroed
    int*         __restrict__ wlist,      // fallback layout only: (NCELLS, CAP)
    int*         __restrict__ ovf_cnt,    // zeroed
    int*         __restrict__ ovf,        // SLOT: cellid ; else (cellid<<17)|pt
    float*       __restrict__ dmin,       // SLOT: (NCELLS,CAP2,48) ; else (N,48)
    float*       __restrict__ dmin_ovf,   // SLOT only: (N,48)
    int n)
{
    __shared__ float4 v_s[PPB * 13];          // p-relative verts (stride 13)
    __shared__ float  gram[PPB * GSTRIDE];    // 12x12 Gram per point slot
    __shared__ int2   goff[NWAVE * NT * 3];   // PER-WAVE packed index table
    __shared__ int    pos_s[PPB];             // SLOT: per-point dmin base

    const int tid  = threadIdx.x;
    const int g    = blockIdx.x * BLK + tid;
    const int pt   = g >> 4;                  // SPLIT=16
    const int grp  = tid & 15;
    const int pl   = tid >> 4;                // slot: wave w owns 4w..4w+3
    const int wid  = tid >> 6;
    const int lane = tid & 63;
    const bool active = (pt < n);

    // Per-wave table copy: lane t (<48) packs entries e = t*3+k, k=0..2.
    // NOT guarded by `active` (tail blocks still need the table).
    if (lane < NT) {
        int2* gw = &goff[wid * (NT * 3)];
        const int t = lane;
#pragma unroll
        for (int k = 0; k < 3; k++) {
            int e  = t * 3 + k;
            int i  = tri_table[e * 3 + 0];
            int j  = tri_table[e * 3 + 1];
            int kk = tri_table[e * 3 + 2];
            gw[e] = make_int2((i * 13) | ((i * 12 + j) << 8) | ((i * 12 + kk) << 16),
                              (j * 13) | ((j * 12 + kk) << 8) | ((kk * 13) << 16));
        }
    }

    float4 vi = make_float4(0.f, 0.f, 0.f, 0.f);
    if (active) {
        float px = points[pt * 3 + 0];
        float py = points[pt * 3 + 1];
        float pz = points[pt * 3 + 2];
        int cx = min(max((int)floorf(px), 0), GRID - 1);
        int cy = min(max((int)floorf(py), 0), GRID - 1);
        int cz = min(max((int)floorf(pz), 0), GRID - 1);
        if (grp == 0) {
            // Fused binning: one int atomic per point.
            int cellid = ((cx * GRID) + cy) * GRID + cz;
            int pos = atomicAdd(&cnt[cellid], 1);
            if (SLOT) {
                int base;
                if (pos < CAP2) base = cellid * CAP2 + pos;
                else { int e = atomicAdd(ovf_cnt, 1); ovf[e] = cellid;
                       base = 0x40000000 | e; }
                pos_s[pl] = base;
            } else {
                if (pos < CAP) wlist[cellid * CAP + pos] = pt;
                else { int e = atomicAdd(ovf_cnt, 1); ovf[e] = (cellid << 17) | pt; }
            }
        }
        if (grp < 12) {
            float lx = px - (float)cx;
            float ly = py - (float)cy;
            float lz = pz - (float)cz;
            unsigned nib = (unsigned)(EDGE_PACK >> (5 * grp)) & 31u;
            int gx = cx + (int)(nib & 1u);
            int gy = cy + (int)((nib >> 1) & 1u);
            int gz = cz + (int)((nib >> 2) & 1u);
            int ax = (int)(nib >> 3);
            float t = offset[((ax * 33 + gx) * 33 + gy) * 33 + gz];
            float vx = (ax == 0) ? t : (float)(nib & 1u);
            float vy = (ax == 1) ? t : (float)((nib >> 1) & 1u);
            float vz = (ax == 2) ? t : (float)((nib >> 2) & 1u);
            vi = make_float4(lx - vx, ly - vy, lz - vz, 0.0f);
            v_s[pl * 13 + grp] = vi;
        }
    }
    // (no __syncthreads: v_s slot is wave-private; lgkmcnt orders write->read)
    // Gram fill: thread grp (<12) computes dots (grp, grp+d mod 12), d=0..6.
    if (active && grp < 12) {
        float* gp = &gram[pl * GSTRIDE];
        int j = grp;
#pragma unroll
        for (int d = 0; d < 7; d++) {
            float4 vj = v_s[pl * 13 + j];
            float dv = fmaf(vi.z, vj.z, fmaf(vi.y, vj.y, vi.x * vj.x));
            gp[grp * 12 + j] = dv;
            gp[j * 12 + grp] = dv;
            j = (j == 11) ? 0 : j + 1;
        }
    }
    // (no __syncthreads: gram slot is wave-private)
    if (!active) return;

    const float* gp = &gram[pl * GSTRIDE];
    const int2* gofft = &goff[wid * (NT * 3) + grp * 9];
    float dm[3];
#pragma unroll
    for (int r = 0; r < 3; r++) {
        float dmn;
#pragma unroll
        for (int k = 0; k < 3; k++) {
            int2 o = gofft[r * 3 + k];
            float AA = gp[o.x & 255];
            float AB = gp[(o.x >> 8) & 255];
            float AC = gp[(unsigned)o.x >> 16];
            float BB = gp[o.y & 255];
            float BC = gp[(o.y >> 8) & 255];
            float CC = gp[(unsigned)o.y >> 16];
            float d = tri_dist_gram(AA, AB, AC, BB, BC, CC);
            dmn = (k == 0) ? d : fminf(dmn, d);
        }
        dm[r] = dmn;
    }
    // Coalesced: each slot's 16 threads write 48 consecutive floats (192B).
    float* dp;
    if (SLOT) {
        int base = pos_s[pl];
        dp = (base & 0x40000000)
               ? &dmin_ovf[(size_t)(base & 0x3FFFFFFF) * NT + grp * 3]
               : &dmin[(size_t)base * NT + grp * 3];
    } else {
        dp = &dmin[(size_t)pt * NT + grp * 3];
    }
    dp[0] = dm[0]; dp[1] = dm[1]; dp[2] = dm[2];
}

// Slot-order reduce: block owns 16 cells; thread (pl,grp) sums 3 t-slots over
// the cell's CONTIGUOUS slot run. No indirection, no atomics.
__global__ __launch_bounds__(BLK) void reduce_slot_kernel(
    const int*   __restrict__ cnt,
    const int*   __restrict__ ovf_cnt,
    const int*   __restrict__ ovf,        // cellid per overflow entry
    const float* __restrict__ dmin,       // (NCELLS, CAP2, 48)
    const float* __restrict__ dmin_ovf,   // (N, 48)
    float*       __restrict__ out)        // (32768,48)
{
    const int tid  = threadIdx.x;
    const int grp  = tid & 15;
    const int pl   = tid >> 4;
    const int cell = blockIdx.x * PPB + pl;

    const int c = min(cnt[cell], CAP2);
    const float* bp = &dmin[(size_t)cell * CAP2 * NT + grp * 3];
    float s0 = 0.f, s1 = 0.f, s2 = 0.f;
    for (int i = 0; i < c; i++) {
        s0 += bp[0]; s1 += bp[1]; s2 += bp[2];
        bp += NT;
    }
    // Overflow items (normally zero; correctness for adversarial inputs).
    const int movf = *ovf_cnt;
    for (int e = 0; e < movf; e++) {
        if (ovf[e] == cell) {
            const float* dp = &dmin_ovf[(size_t)e * NT + grp * 3];
            s0 += dp[0]; s1 += dp[1]; s2 += dp[2];
        }
    }
    float* op = &out[cell * NT + grp * 3];
    op[0] = s0; op[1] = s1; op[2] = s2;
}

// Fallback reduce: wlist indirection, point-major dmin.
__global__ __launch_bounds__(BLK) void reduce_kernel(
    const int*   __restrict__ cnt,
    const int*   __restrict__ wlist,
    const int*   __restrict__ ovf_cnt,
    const int*   __restrict__ ovf,
    const float* __restrict__ dmin,
    float*       __restrict__ out)
{
    const int tid  = threadIdx.x;
    const int grp  = tid & 15;
    const int pl   = tid >> 4;
    const int cell = blockIdx.x * PPB + pl;

    const int c = min(cnt[cell], CAP);
    const int* wl = &wlist[cell * CAP];
    float s0 = 0.f, s1 = 0.f, s2 = 0.f;
    for (int i = 0; i < c; i++) {
        int pt = wl[i];
        const float* dp = &dmin[(size_t)pt * NT + grp * 3];
        s0 += dp[0]; s1 += dp[1]; s2 += dp[2];
    }
    const int movf = *ovf_cnt;
    for (int e = 0; e < movf; e++) {
        int v = ovf[e];
        if ((v >> 17) == cell) {
            int pt = v & 0x1FFFF;
            const float* dp = &dmin[(size_t)pt * NT + grp * 3];
            s0 += dp[0]; s1 += dp[1]; s2 += dp[2];
        }
    }
    float* op = &out[cell * NT + grp * 3];
    op[0] = s0; op[1] = s1; op[2] = s2;
}

// ----- last-resort fallback (round-1 kernel, global atomics; round-4 form) ---
__global__ __launch_bounds__(BLK) void ptd_kernel(
    const float* __restrict__ offset,
    const float* __restrict__ points,
    const int*   __restrict__ tri_table,
    float*       __restrict__ out,
    int n)
{
    __shared__ float4 v_s[PPB * 13];
    __shared__ float  gram[PPB * GSTRIDE];
    __shared__ int2   goff[NT * 3];

    const int tid = threadIdx.x;
    const int g   = blockIdx.x * BLK + tid;
    const int pt  = g >> 4;
    const int grp = tid & 15;
    const int pl  = tid >> 4;
    const bool active = (pt < n);

    if (tid < NT * 3) {
        int i = tri_table[tid * 3 + 0];
        int j = tri_table[tid * 3 + 1];
        int k = tri_table[tid * 3 + 2];
        goff[tid] = make_int2((i * 13) | ((i * 12 + j) << 8) | ((i * 12 + k) << 16),
                              (j * 13) | ((j * 12 + k) << 8) | ((k * 13) << 16));
    }

    float4 vi = make_float4(0.f, 0.f, 0.f, 0.f);
    int cx = 0, cy = 0, cz = 0;
    if (active) {
        float px = points[pt * 3 + 0];
        float py = points[pt * 3 + 1];
        float pz = points[pt * 3 + 2];
        cx = min(max((int)floorf(px), 0), GRID - 1);
        cy = min(max((int)floorf(py), 0), GRID - 1);
        cz = min(max((int)floorf(pz), 0), GRID - 1);
        if (grp < 12) {
            float lx = px - (float)cx;
            float ly = py - (float)cy;
            float lz = pz - (float)cz;
            unsigned nib = (unsigned)(EDGE_PACK >> (5 * grp)) & 31u;
            int gx = cx + (int)(nib & 1u);
            int gy = cy + (int)((nib >> 1) & 1u);
            int gz = cz + (int)((nib >> 2) & 1u);
            int ax = (int)(nib >> 3);
            float t = offset[((ax * 33 + gx) * 33 + gy) * 33 + gz];
            float vx = (ax == 0) ? t : (float)(nib & 1u);
            float vy = (ax == 1) ? t : (float)((nib >> 1) & 1u);
            float vz = (ax == 2) ? t : (float)((nib >> 2) & 1u);
            vi = make_float4(lx - vx, ly - vy, lz - vz, 0.0f);
            v_s[pl * 13 + grp] = vi;
        }
    }
    __syncthreads();
    if (active && grp < 12) {
        float* gp = &gram[pl * GSTRIDE];
        int j = grp;
#pragma unroll
        for (int d = 0; d < 7; d++) {
            float4 vj = v_s[pl * 13 + j];
            float dv = fmaf(vi.z, vj.z, fmaf(vi.y, vj.y, vi.x * vj.x));
            gp[grp * 12 + j] = dv;
            gp[j * 12 + grp] = dv;
            j = (j == 11) ? 0 : j + 1;
        }
    }
    __syncthreads();
    if (!active) return;

    const float* gp = &gram[pl * GSTRIDE];
    float* outp = out + ((((cx * GRID) + cy) * GRID + cz) * NT);
    const int2* gofft = &goff[grp * 9];
#pragma unroll
    for (int r = 0; r < 3; r++) {
        float dmn;
#pragma unroll
        for (int k = 0; k < 3; k++) {
            int2 o = gofft[r * 3 + k];
            float AA = gp[o.x & 255];
            float AB = gp[(o.x >> 8) & 255];
            float AC = gp[(unsigned)o.x >> 16];
            float BB = gp[o.y & 255];
            float BC = gp[(o.y >> 8) & 255];
            float CC = gp[(unsigned)o.y >> 16];
            float d = tri_dist_gram(AA, AB, AC, BB, BC, CC);
            dmn = (k == 0) ? d : fminf(dmn, d);
        }
        atomicAdd(&outp[grp * 3 + r], dmn);
    }
}

extern "C" void kernel_launch(void* const* d_in, const int* in_sizes, int n_in,
                              void* d_out, int out_size, void* d_ws, size_t ws_size,
                              hipStream_t stream) {
    const float* offset    = (const float*)d_in[0];
    const float* points    = (const float*)d_in[1];
    const int*   tri_table = (const int*)d_in[2];
    float* out = (float*)d_out;
    int n = in_sizes[1] / 3;  // 131072 points

    // Common prefix: cnt[NCELLS] | ovf_cnt+pad | ovf[n]
    const size_t CNT_BYTES = (size_t)NCELLS * 4;
    const size_t OVFC_OFF  = CNT_BYTES;
    const size_t OVF_OFF   = CNT_BYTES + 128;
    const size_t TAIL_OFF  = (OVF_OFF + (size_t)n * 4 + 255) & ~(size_t)255;

    // Slot-order layout: dmin2[NCELLS*CAP2*48] | dmin_ovf[n*48]
    const size_t DMIN2_BYTES = (size_t)NCELLS * CAP2 * NT * 4;   // ~100.7 MB
    const size_t DOVF_OFF    = TAIL_OFF + DMIN2_BYTES;
    const size_t WS_SLOT     = DOVF_OFF + (size_t)n * NT * 4;

    // Fallback layout: wlist[NCELLS*CAP] | dmin[n*48]
    const size_t WL_BYTES = (size_t)NCELLS * CAP * 4;            // 4 MB
    const size_t DMIN_OFF = TAIL_OFF + WL_BYTES;
    const size_t WS_FB    = DMIN_OFF + (size_t)n * NT * 4;

    char* ws = (char*)d_ws;
    int* cnt     = (int*)(ws);
    int* ovf_cnt = (int*)(ws + OVFC_OFF);
    int* ovf     = (int*)(ws + OVF_OFF);

    long total = (long)n * SPLIT;
    int blocks = (int)((total + BLK - 1) / BLK);

    if (ws_size >= WS_SLOT) {
        float* dmin2    = (float*)(ws + TAIL_OFF);
        float* dmin_ovf = (float*)(ws + DOVF_OFF);
        hipMemsetAsync(ws, 0, OVF_OFF, stream);   // cnt + ovf_cnt
        eval_kernel<true><<<blocks, BLK, 0, stream>>>(
            offset, points, tri_table, cnt, nullptr, ovf_cnt, ovf,
            dmin2, dmin_ovf, n);
        reduce_slot_kernel<<<NCELLS / PPB, BLK, 0, stream>>>(
            cnt, ovf_cnt, ovf, dmin2, dmin_ovf, out);
    } else if (ws_size >= WS_FB) {
        int*   wlist = (int*)(ws + TAIL_OFF);
        float* dmin  = (float*)(ws + DMIN_OFF);
        hipMemsetAsync(ws, 0, OVF_OFF, stream);
        eval_kernel<false><<<blocks, BLK, 0, stream>>>(
            offset, points, tri_table, cnt, wlist, ovf_cnt, ovf,
            dmin, nullptr, n);
        reduce_kernel<<<NCELLS / PPB, BLK, 0, stream>>>(
            cnt, wlist, ovf_cnt, ovf, dmin, out);
    } else {
        // Last resort: per-point kernel with global atomics.
        hipMemsetAsync(d_out, 0, (size_t)out_size * sizeof(float), stream);
        ptd_kernel<<<blocks, BLK, 0, stream>>>(offset, points, tri_table, out, n);
    }
}

// Round 9
// 110.219 us; speedup vs baseline: 1.0211x; 1.0211x over previous
//
#include <hip/hip_runtime.h>

#define GRID 32
#define NT 48
#define BLK 256
#define SPLIT 16                 // threads per point; each handles 3 t-rows = 9 tris
#define PPB (BLK / SPLIT)        // 16 points per block
#define NCELLS (GRID * GRID * GRID)
#define CAP 32                   // fallback wlist capacity
#define CAP2 16                  // slot-order dmin capacity (Poisson(4): P(>16) ~ 1e-6)
#define GSTRIDE 144              // gram slot stride (r4-verified layout)

// Per-edge packed info: bits [0]=base_x, [1]=base_y, [2]=base_z, [4:3]=axis.
// EDGE_BASE[e][axis[e]] == 0 for all 12 edges, so vert = base with comp[axis]=t.
#define EDGE_PACK ( (0ULL<<0) | (9ULL<<5) | (2ULL<<10) | (8ULL<<15) | \
                    (4ULL<<20) | (13ULL<<25) | (6ULL<<30) | (12ULL<<35) | \
                    (16ULL<<40) | (17ULL<<45) | (19ULL<<50) | (18ULL<<55) )

// Squared distance from p to triangle (a,b,c) from the 6 Gram entries of
// Ap=p-a, Bp=p-b, Cp=p-c. Region cascade matches the reference order exactly;
// vertex regions collapse exactly to AA/BB/CC and are applied as cascade-
// ordered overrides. Round-9: region conditions rewritten in min3/max3 form
// (v_min3_f32 with input modifiers) — per-condition equivalence:
//   cbc: (va<=0)&(d43>=0)&(d56>=0)  == min(-va,d43,d56) >= 0
//   cac: (vb<=0)&(d2>=0)&(d6<=0)    == min(-vb,d2,-d6)  >= 0
//   ccc: (d6>=0)&(d5<=d6)           == min(d6,-d56) >= 0   [d56 == d5-d6]
//   cab: (vc<=0)&(d1>=0)&(d3<=0)    == min(-vc,d1,-d3) >= 0
//   cbb: (d3>=0)&(d4<=d3)           == min(d3,-d43) >= 0   [d43 == d4-d3]
//   caa: (d1<=0)&(d2<=0)            == max(d1,d2) <= 0
// (+-0 cases match: -0 >= 0 is true, as was 0 <= 0; inputs are finite.)
// Value/select chains are VERBATIM round-4 verified text (absmax 0.0039).
__device__ __forceinline__ float tri_dist_gram(float AA, float AB, float AC,
                                               float BB, float BC, float CC) {
    float d1 = AA - AB, d2 = AA - AC;
    float d3 = AB - BB, d4 = AB - BC;
    float d5 = AC - BC, d6 = AC - CC;
    float d43 = BB - BC;          // == d4 - d3
    float d56 = CC - BC;          // == d5 - d6
    float vc = d1 * d4 - d3 * d2;
    float vb = d5 * d2 - d1 * d6;
    float va = d3 * d6 - d5 * d4;

    bool cbc = fminf(fminf(-va, d43), d56) >= 0.f;
    bool cac = fminf(fminf(-vb, d2), -d6) >= 0.f;
    bool ccc = fminf(d6, -d56) >= 0.f;
    bool cab = fminf(fminf(-vc, d1), -d3) >= 0.f;
    bool cbb = fminf(d3, -d43) >= 0.f;
    bool caa = fmaxf(d1, d2) <= 0.f;

    // Chain (later wins): interior -> cbc -> cac -> cab.
    float nv = vb, nw = vc, den = va + vb + vc;
    nw = cbc ? d43 : nw;  den = cbc ? d43 + d56 : den;
    nv = cac ? 0.f : nv;  nw = cac ? d2  : nw;  den = cac ? d2 - d6 : den;
    nv = cab ? d1  : nv;  nw = cab ? 0.f : nw;  den = cab ? d1 - d3 : den;
    bool mode = cbc & !cac & !cab;   // only cbc uses lambda = (0, 1-w, w)

    float dd  = (fabsf(den) > 1e-12f) ? den : 1e-12f;
    float inv = __builtin_amdgcn_rcpf(dd);
    float vp = nv * inv;
    float wp = nw * inv;
    float u = mode ? 0.f : 1.f - vp - wp;
    float v = mode ? 1.f - wp : vp;
    float e1 = fmaf(AC, wp, fmaf(AB, v, AA * u));
    float e2 = fmaf(BC, wp, fmaf(BB, v, AB * u));
    float e3 = fmaf(CC, wp, fmaf(BC, v, AC * u));
    float r  = fmaf(wp, e3, fmaf(v, e2, u * e1));
    // Vertex-region overrides, cascade-ordered.
    r = (ccc & !cab) ? CC : r;
    r = cbb ? BB : r;
    r = caa ? AA : r;
    return r;
}

// Point-major eval (round-4 verified delivery: 2 barriers, 144-stride gram,
// simple k-loop). SLOT=true: binning assigns each point a (cell,pos) slot and
// dmin is stored slot-ordered (dmin[cell][pos][48]); SLOT=false: dmin[pt][48]
// + wlist. Round-9: goff fields are PRE-SCALED byte offsets (idx*4, 10-bit
// fields) so per-load unpack is and/shr+add with no shift.
template<bool SLOT>
__global__ __launch_bounds__(BLK) void eval_kernel(
    const float* __restrict__ offset,     // (3,33,33,33)
    const float* __restrict__ points,     // (N,3)
    const int*   __restrict__ tri_table,  // (48,3,3)
    int*         __restrict__ cnt,        // (NCELLS), zeroed
    int*         __restrict__ wlist,      // fallback layout only: (NCELLS, CAP)
    int*         __restrict__ ovf_cnt,    // zeroed
    int*         __restrict__ ovf,        // SLOT: cellid ; else (cellid<<17)|pt
    float*       __restrict__ dmin,       // SLOT: (NCELLS,CAP2,48) ; else (N,48)
    float*       __restrict__ dmin_ovf,   // SLOT only: (N,48)
    int n)
{
    __shared__ float4 v_s[PPB * 13];      // p-relative verts (12 used, stride 13)
    __shared__ float  gram[PPB * GSTRIDE];// 12x12 symmetric Gram per point slot
    __shared__ int2   goff[NT * 3];       // per (t,k): 6 packed 10-bit byte offsets
    __shared__ int    pos_s[PPB];         // SLOT: per-point dmin base (or ovf flag)

    const int tid = threadIdx.x;
    const int g   = blockIdx.x * BLK + tid;
    const int pt  = g >> 4;               // SPLIT=16
    const int grp = tid & 15;
    const int pl  = tid >> 4;
    const bool active = (pt < n);

    // Pre-scaled byte offsets: field = idx*4 (max 11*13*4 = 572 < 1024).
    if (tid < NT * 3) {
        int i = tri_table[tid * 3 + 0];
        int j = tri_table[tid * 3 + 1];
        int k = tri_table[tid * 3 + 2];
        goff[tid] = make_int2(
            (i * 13 * 4) | (((i * 12 + j) * 4) << 10) | (((i * 12 + k) * 4) << 20),
            (j * 13 * 4) | (((j * 12 + k) * 4) << 10) | ((k * 13 * 4) << 20));
    }

    float4 vi = make_float4(0.f, 0.f, 0.f, 0.f);
    if (active) {
        float px = points[pt * 3 + 0];
        float py = points[pt * 3 + 1];
        float pz = points[pt * 3 + 2];
        int cx = min(max((int)floorf(px), 0), GRID - 1);
        int cy = min(max((int)floorf(py), 0), GRID - 1);
        int cz = min(max((int)floorf(pz), 0), GRID - 1);
        if (grp == 0) {
            // Fused binning: one int atomic per point.
            int cellid = ((cx * GRID) + cy) * GRID + cz;
            int pos = atomicAdd(&cnt[cellid], 1);
            if (SLOT) {
                int base;
                if (pos < CAP2) base = cellid * CAP2 + pos;
                else { int e = atomicAdd(ovf_cnt, 1); ovf[e] = cellid;
                       base = 0x40000000 | e; }
                pos_s[pl] = base;
            } else {
                if (pos < CAP) wlist[cellid * CAP + pos] = pt;
                else { int e = atomicAdd(ovf_cnt, 1); ovf[e] = (cellid << 17) | pt; }
            }
        }
        if (grp < 12) {
            float lx = px - (float)cx;
            float ly = py - (float)cy;
            float lz = pz - (float)cz;
            unsigned nib = (unsigned)(EDGE_PACK >> (5 * grp)) & 31u;
            int gx = cx + (int)(nib & 1u);
            int gy = cy + (int)((nib >> 1) & 1u);
            int gz = cz + (int)((nib >> 2) & 1u);
            int ax = (int)(nib >> 3);
            float t = offset[((ax * 33 + gx) * 33 + gy) * 33 + gz];
            float vx = (ax == 0) ? t : (float)(nib & 1u);
            float vy = (ax == 1) ? t : (float)((nib >> 1) & 1u);
            float vz = (ax == 2) ? t : (float)((nib >> 2) & 1u);
            vi = make_float4(lx - vx, ly - vy, lz - vz, 0.0f);
            v_s[pl * 13 + grp] = vi;
        }
    }
    __syncthreads();
    // Gram fill: thread grp (<12) computes dots (grp, grp+d mod 12), d=0..6.
    if (active && grp < 12) {
        float* gp = &gram[pl * GSTRIDE];
        int j = grp;
#pragma unroll
        for (int d = 0; d < 7; d++) {
            float4 vj = v_s[pl * 13 + j];
            float dv = fmaf(vi.z, vj.z, fmaf(vi.y, vj.y, vi.x * vj.x));
            gp[grp * 12 + j] = dv;
            gp[j * 12 + grp] = dv;
            j = (j == 11) ? 0 : j + 1;
        }
    }
    __syncthreads();
    if (!active) return;

    const char* gb = (const char*)&gram[pl * GSTRIDE];
    const int2* gofft = &goff[grp * 9];
    float dm[3];
#pragma unroll
    for (int r = 0; r < 3; r++) {
        float dmn;
#pragma unroll
        for (int k = 0; k < 3; k++) {
            int2 o = gofft[r * 3 + k];
            float AA = *(const float*)(gb + (o.x & 1023));
            float AB = *(const float*)(gb + ((o.x >> 10) & 1023));
            float AC = *(const float*)(gb + ((unsigned)o.x >> 20));
            float BB = *(const float*)(gb + (o.y & 1023));
            float BC = *(const float*)(gb + ((o.y >> 10) & 1023));
            float CC = *(const float*)(gb + ((unsigned)o.y >> 20));
            float d = tri_dist_gram(AA, AB, AC, BB, BC, CC);
            dmn = (k == 0) ? d : fminf(dmn, d);
        }
        dm[r] = dmn;
    }
    // Coalesced: each slot's 16 threads write 48 consecutive floats (192B).
    float* dp;
    if (SLOT) {
        int base = pos_s[pl];
        dp = (base & 0x40000000)
               ? &dmin_ovf[(size_t)(base & 0x3FFFFFFF) * NT + grp * 3]
               : &dmin[(size_t)base * NT + grp * 3];
    } else {
        dp = &dmin[(size_t)pt * NT + grp * 3];
    }
    dp[0] = dm[0]; dp[1] = dm[1]; dp[2] = dm[2];
}

// Slot-order reduce: block owns 16 cells; thread (pl,grp) sums 3 t-slots over
// the cell's CONTIGUOUS slot run. No indirection, no atomics.
__global__ __launch_bounds__(BLK) void reduce_slot_kernel(
    const int*   __restrict__ cnt,
    const int*   __restrict__ ovf_cnt,
    const int*   __restrict__ ovf,        // cellid per overflow entry
    const float* __restrict__ dmin,       // (NCELLS, CAP2, 48)
    const float* __restrict__ dmin_ovf,   // (N, 48)
    float*       __restrict__ out)        // (32768,48)
{
    const int tid  = threadIdx.x;
    const int grp  = tid & 15;
    const int pl   = tid >> 4;
    const int cell = blockIdx.x * PPB + pl;

    const int c = min(cnt[cell], CAP2);
    const float* bp = &dmin[(size_t)cell * CAP2 * NT + grp * 3];
    float s0 = 0.f, s1 = 0.f, s2 = 0.f;
    for (int i = 0; i < c; i++) {
        s0 += bp[0]; s1 += bp[1]; s2 += bp[2];
        bp += NT;
    }
    // Overflow items (normally zero; correctness for adversarial inputs).
    const int movf = *ovf_cnt;
    for (int e = 0; e < movf; e++) {
        if (ovf[e] == cell) {
            const float* dp = &dmin_ovf[(size_t)e * NT + grp * 3];
            s0 += dp[0]; s1 += dp[1]; s2 += dp[2];
        }
    }
    float* op = &out[cell * NT + grp * 3];
    op[0] = s0; op[1] = s1; op[2] = s2;
}

// Fallback reduce: wlist indirection, point-major dmin.
__global__ __launch_bounds__(BLK) void reduce_kernel(
    const int*   __restrict__ cnt,
    const int*   __restrict__ wlist,
    const int*   __restrict__ ovf_cnt,
    const int*   __restrict__ ovf,
    const float* __restrict__ dmin,
    float*       __restrict__ out)
{
    const int tid  = threadIdx.x;
    const int grp  = tid & 15;
    const int pl   = tid >> 4;
    const int cell = blockIdx.x * PPB + pl;

    const int c = min(cnt[cell], CAP);
    const int* wl = &wlist[cell * CAP];
    float s0 = 0.f, s1 = 0.f, s2 = 0.f;
    for (int i = 0; i < c; i++) {
        int pt = wl[i];
        const float* dp = &dmin[(size_t)pt * NT + grp * 3];
        s0 += dp[0]; s1 += dp[1]; s2 += dp[2];
    }
    const int movf = *ovf_cnt;
    for (int e = 0; e < movf; e++) {
        int v = ovf[e];
        if ((v >> 17) == cell) {
            int pt = v & 0x1FFFF;
            const float* dp = &dmin[(size_t)pt * NT + grp * 3];
            s0 += dp[0]; s1 += dp[1]; s2 += dp[2];
        }
    }
    float* op = &out[cell * NT + grp * 3];
    op[0] = s0; op[1] = s1; op[2] = s2;
}

// ----- last-resort fallback (round-1 kernel, global atomics; round-4 form) ---
__global__ __launch_bounds__(BLK) void ptd_kernel(
    const float* __restrict__ offset,
    const float* __restrict__ points,
    const int*   __restrict__ tri_table,
    float*       __restrict__ out,
    int n)
{
    __shared__ float4 v_s[PPB * 13];
    __shared__ float  gram[PPB * GSTRIDE];
    __shared__ int2   goff[NT * 3];

    const int tid = threadIdx.x;
    const int g   = blockIdx.x * BLK + tid;
    const int pt  = g >> 4;
    const int grp = tid & 15;
    const int pl  = tid >> 4;
    const bool active = (pt < n);

    if (tid < NT * 3) {
        int i = tri_table[tid * 3 + 0];
        int j = tri_table[tid * 3 + 1];
        int k = tri_table[tid * 3 + 2];
        goff[tid] = make_int2((i * 13) | ((i * 12 + j) << 8) | ((i * 12 + k) << 16),
                              (j * 13) | ((j * 12 + k) << 8) | ((k * 13) << 16));
    }

    float4 vi = make_float4(0.f, 0.f, 0.f, 0.f);
    int cx = 0, cy = 0, cz = 0;
    if (active) {
        float px = points[pt * 3 + 0];
        float py = points[pt * 3 + 1];
        float pz = points[pt * 3 + 2];
        cx = min(max((int)floorf(px), 0), GRID - 1);
        cy = min(max((int)floorf(py), 0), GRID - 1);
        cz = min(max((int)floorf(pz), 0), GRID - 1);
        if (grp < 12) {
            float lx = px - (float)cx;
            float ly = py - (float)cy;
            float lz = pz - (float)cz;
            unsigned nib = (unsigned)(EDGE_PACK >> (5 * grp)) & 31u;
            int gx = cx + (int)(nib & 1u);
            int gy = cy + (int)((nib >> 1) & 1u);
            int gz = cz + (int)((nib >> 2) & 1u);
            int ax = (int)(nib >> 3);
            float t = offset[((ax * 33 + gx) * 33 + gy) * 33 + gz];
            float vx = (ax == 0) ? t : (float)(nib & 1u);
            float vy = (ax == 1) ? t : (float)((nib >> 1) & 1u);
            float vz = (ax == 2) ? t : (float)((nib >> 2) & 1u);
            vi = make_float4(lx - vx, ly - vy, lz - vz, 0.0f);
            v_s[pl * 13 + grp] = vi;
        }
    }
    __syncthreads();
    if (active && grp < 12) {
        float* gp = &gram[pl * GSTRIDE];
        int j = grp;
#pragma unroll
        for (int d = 0; d < 7; d++) {
            float4 vj = v_s[pl * 13 + j];
            float dv = fmaf(vi.z, vj.z, fmaf(vi.y, vj.y, vi.x * vj.x));
            gp[grp * 12 + j] = dv;
            gp[j * 12 + grp] = dv;
            j = (j == 11) ? 0 : j + 1;
        }
    }
    __syncthreads();
    if (!active) return;

    const float* gp = &gram[pl * GSTRIDE];
    float* outp = out + ((((cx * GRID) + cy) * GRID + cz) * NT);
    const int2* gofft = &goff[grp * 9];
#pragma unroll
    for (int r = 0; r < 3; r++) {
        float dmn;
#pragma unroll
        for (int k = 0; k < 3; k++) {
            int2 o = gofft[r * 3 + k];
            float AA = gp[o.x & 255];
            float AB = gp[(o.x >> 8) & 255];
            float AC = gp[(unsigned)o.x >> 16];
            float BB = gp[o.y & 255];
            float BC = gp[(o.y >> 8) & 255];
            float CC = gp[(unsigned)o.y >> 16];
            float d = tri_dist_gram(AA, AB, AC, BB, BC, CC);
            dmn = (k == 0) ? d : fminf(dmn, d);
        }
        atomicAdd(&outp[grp * 3 + r], dmn);
    }
}

extern "C" void kernel_launch(void* const* d_in, const int* in_sizes, int n_in,
                              void* d_out, int out_size, void* d_ws, size_t ws_size,
                              hipStream_t stream) {
    const float* offset    = (const float*)d_in[0];
    const float* points    = (const float*)d_in[1];
    const int*   tri_table = (const int*)d_in[2];
    float* out = (float*)d_out;
    int n = in_sizes[1] / 3;  // 131072 points

    // Common prefix: cnt[NCELLS] | ovf_cnt+pad | ovf[n]
    const size_t CNT_BYTES = (size_t)NCELLS * 4;
    const size_t OVFC_OFF  = CNT_BYTES;
    const size_t OVF_OFF   = CNT_BYTES + 128;
    const size_t TAIL_OFF  = (OVF_OFF + (size_t)n * 4 + 255) & ~(size_t)255;

    // Slot-order layout: dmin2[NCELLS*CAP2*48] | dmin_ovf[n*48]
    const size_t DMIN2_BYTES = (size_t)NCELLS * CAP2 * NT * 4;   // ~100.7 MB
    const size_t DOVF_OFF    = TAIL_OFF + DMIN2_BYTES;
    const size_t WS_SLOT     = DOVF_OFF + (size_t)n * NT * 4;

    // Fallback layout: wlist[NCELLS*CAP] | dmin[n*48]
    const size_t WL_BYTES = (size_t)NCELLS * CAP * 4;            // 4 MB
    const size_t DMIN_OFF = TAIL_OFF + WL_BYTES;
    const size_t WS_FB    = DMIN_OFF + (size_t)n * NT * 4;

    char* ws = (char*)d_ws;
    int* cnt     = (int*)(ws);
    int* ovf_cnt = (int*)(ws + OVFC_OFF);
    int* ovf     = (int*)(ws + OVF_OFF);

    long total = (long)n * SPLIT;
    int blocks = (int)((total + BLK - 1) / BLK);

    if (ws_size >= WS_SLOT) {
        float* dmin2    = (float*)(ws + TAIL_OFF);
        float* dmin_ovf = (float*)(ws + DOVF_OFF);
        hipMemsetAsync(ws, 0, OVF_OFF, stream);   // cnt + ovf_cnt
        eval_kernel<true><<<blocks, BLK, 0, stream>>>(
            offset, points, tri_table, cnt, nullptr, ovf_cnt, ovf,
            dmin2, dmin_ovf, n);
        reduce_slot_kernel<<<NCELLS / PPB, BLK, 0, stream>>>(
            cnt, ovf_cnt, ovf, dmin2, dmin_ovf, out);
    } else if (ws_size >= WS_FB) {
        int*   wlist = (int*)(ws + TAIL_OFF);
        float* dmin  = (float*)(ws + DMIN_OFF);
        hipMemsetAsync(ws, 0, OVF_OFF, stream);
        eval_kernel<false><<<blocks, BLK, 0, stream>>>(
            offset, points, tri_table, cnt, wlist, ovf_cnt, ovf,
            dmin, nullptr, n);
        reduce_kernel<<<NCELLS / PPB, BLK, 0, stream>>>(
            cnt, wlist, ovf_cnt, ovf, dmin, out);
    } else {
        // Last resort: per-point kernel with global atomics.
        hipMemsetAsync(d_out, 0, (size_t)out_size * sizeof(float), stream);
        ptd_kernel<<<blocks, BLK, 0, stream>>>(offset, points, tri_table, out, n);
    }
}